// Round 23
// baseline (197.776 us; speedup 1.0000x reference)
//
#include <hip/hip_runtime.h>
#include <hip/hip_bf16.h>

// GCN forward: out = spmm(A, relu(spmm(A, x@W1)+b1) @ W2) + b2
// N=50000, F=512, H=128, C=40, E=800000
// Round 23: fix round-22 failure. spmm1_slice's per-group edge loop had
// group-divergent trip counts; __shfl (ds_bpermute) returns UNDEFINED data
// from EXEC-inactive source lanes, so the leading group read garbage slots
// on its extra iterations (absmax 0.129). Loop is now wave-uniform
// (iters=ceil(dg/4), clamped source lane, weight zeroed for j>=dg).

#define NFEAT 512
#define NHID  128
#define NCLS  40
#define BSH   8            // 256 dsts per bucket
#define SLOTSH 6           // 64 edge slots per node (max deg ~40)
#define BSLOT 6144         // bucket scratch slots (mean 4082, +32 sigma)
#define ACHUNK 2048        // edges per bucketize block

typedef __attribute__((ext_vector_type(8))) short bf16x8;
typedef __attribute__((ext_vector_type(4))) float f32x4;
typedef __fp16 cvt16x2 __attribute__((ext_vector_type(2)));    // builtin boundary
typedef _Float16 h16x2 __attribute__((ext_vector_type(2)));    // packed arithmetic

__device__ inline short f2bf(float f) {
  __hip_bfloat16 b = __float2bfloat16(f);
  return *reinterpret_cast<short*>(&b);
}

__device__ inline bf16x8 cvt8(float4 a, float4 b) {
  bf16x8 r;
  r[0] = f2bf(a.x); r[1] = f2bf(a.y); r[2] = f2bf(a.z); r[3] = f2bf(a.w);
  r[4] = f2bf(b.x); r[5] = f2bf(b.y); r[6] = f2bf(b.z); r[7] = f2bf(b.w);
  return r;
}

__device__ inline unsigned pk2u(cvt16x2 v) { union { cvt16x2 h; unsigned u; } x; x.h = v; return x.u; }
__device__ inline h16x2   u2a(unsigned u)  { union { h16x2 h; unsigned u; } x; x.u = u; return x.h; }

// ---------------- w1t + zero (fused) ----------------
__global__ __launch_bounds__(256) void w1t_zero(
    const float* __restrict__ W1, __hip_bfloat16* __restrict__ W1t,
    int4* __restrict__ zp, int n4) {
  __shared__ float t[64][129];
  const int tid = threadIdx.x;
  if (blockIdx.x < 8) {
    const int k0 = blockIdx.x * 64;
#pragma unroll
    for (int i = 0; i < 8; ++i) {
      int f = i * 256 + tid;
      int r = f >> 5, c = (f & 31) << 2;
      float4 v = *(const float4*)&W1[(size_t)(k0 + r) * NHID + c];
      t[r][c] = v.x; t[r][c + 1] = v.y; t[r][c + 2] = v.z; t[r][c + 3] = v.w;
    }
    __syncthreads();
#pragma unroll
    for (int i = 0; i < 32; ++i) {
      int o = i * 256 + tid;
      int k = o & 63, n = o >> 6;
      W1t[(size_t)n * NFEAT + k0 + k] = __float2bfloat16(t[k][n]);
    }
  } else {
    int i = (blockIdx.x - 8) * 256 + tid;
    if (i < n4) zp[i] = make_int4(0, 0, 0, 0);
  }
}

// ---------------- FAT kernel bodies ----------------
__device__ __forceinline__ void gemm1_body(
    char* smem, const float* __restrict__ x, const __hip_bfloat16* __restrict__ W1t,
    _Float16* __restrict__ support, int nrows, int bid) {
  char* sA0 = smem;                 // 2 x 8KB  = [0, 16K)
  char* sB0 = smem + 16384;         // 2 x 16KB = [16K, 48K)
  const int tid = threadIdx.x;
  const int lane = tid & 63;
  const int wid = tid >> 6;
  const int wm = wid >> 1, wn = wid & 1;
  const int row0 = bid * 64;
  const int l15 = lane & 15, l4 = lane >> 4;

  const int s_ar = tid >> 2;
  const int s_ac = (tid & 3) * 16;
  const int s_br = tid >> 1;
  const int s_bc = (tid & 1) * 32;
  const bool a_ok = (row0 + s_ar) < nrows;
  const float* aptr = &x[(size_t)(row0 + s_ar) * NFEAT + s_ac];
  const uint4* bptr = (const uint4*)&W1t[(size_t)s_br * NFEAT + s_bc];

  f32x4 acc[2][4];
#pragma unroll
  for (int m = 0; m < 2; ++m)
#pragma unroll
    for (int n = 0; n < 4; ++n) acc[m][n] = (f32x4){0.f, 0.f, 0.f, 0.f};

  float4 ra0[4], ra1[4];
  uint4 rb0[4], rb1[4];

  auto LOADAB = [&](int kt, int sel) {
    if (sel == 0) {
      if (a_ok) {
        const float4* p = (const float4*)(aptr + (size_t)kt * 64);
#pragma unroll
        for (int i = 0; i < 4; ++i) ra0[i] = p[i];
      } else {
        float4 z = make_float4(0.f, 0.f, 0.f, 0.f);
#pragma unroll
        for (int i = 0; i < 4; ++i) ra0[i] = z;
      }
      const uint4* q = bptr + (size_t)kt * 8;
#pragma unroll
      for (int i = 0; i < 4; ++i) rb0[i] = q[i];
    } else {
      if (a_ok) {
        const float4* p = (const float4*)(aptr + (size_t)kt * 64);
#pragma unroll
        for (int i = 0; i < 4; ++i) ra1[i] = p[i];
      } else {
        float4 z = make_float4(0.f, 0.f, 0.f, 0.f);
#pragma unroll
        for (int i = 0; i < 4; ++i) ra1[i] = z;
      }
      const uint4* q = bptr + (size_t)kt * 8;
#pragma unroll
      for (int i = 0; i < 4; ++i) rb1[i] = q[i];
    }
  };
  auto WRITE = [&](int buf, int sel) {
    bf16x8 c0, c1;
    if (sel == 0) { c0 = cvt8(ra0[0], ra0[1]); c1 = cvt8(ra0[2], ra0[3]); }
    else          { c0 = cvt8(ra1[0], ra1[1]); c1 = cvt8(ra1[2], ra1[3]); }
    int swa = (s_ar & 7) << 4;
    char* sA = sA0 + buf * 8192;
    *(bf16x8*)(sA + ((s_ar * 128 + s_ac * 2) ^ swa)) = c0;
    *(bf16x8*)(sA + ((s_ar * 128 + s_ac * 2 + 16) ^ swa)) = c1;
    int swb = (s_br & 7) << 4;
    char* sB = sB0 + buf * 16384;
#pragma unroll
    for (int i = 0; i < 4; ++i) {
      uint4 v = (sel == 0) ? rb0[i] : rb1[i];
      *(uint4*)(sB + ((s_br * 128 + s_bc * 2 + i * 16) ^ swb)) = v;
    }
  };
  auto COMP = [&](int buf) {
    char* sA = sA0 + buf * 8192;
    char* sB = sB0 + buf * 16384;
#pragma unroll
    for (int kk = 0; kk < 64; kk += 32) {
      bf16x8 a[2], b[4];
      int cb = (kk + l4 * 8) * 2;
#pragma unroll
      for (int m = 0; m < 2; ++m) {
        int r = wm * 32 + m * 16 + l15;
        a[m] = *(const bf16x8*)(sA + ((r * 128 + cb) ^ ((r & 7) << 4)));
      }
#pragma unroll
      for (int n = 0; n < 4; ++n) {
        int r = wn * 64 + n * 16 + l15;
        b[n] = *(const bf16x8*)(sB + ((r * 128 + cb) ^ ((r & 7) << 4)));
      }
#pragma unroll
      for (int m = 0; m < 2; ++m)
#pragma unroll
        for (int n = 0; n < 4; ++n)
          acc[m][n] = __builtin_amdgcn_mfma_f32_16x16x32_bf16(a[m], b[n], acc[m][n], 0, 0, 0);
    }
  };
  auto BAR = [&]() {
    asm volatile("s_waitcnt lgkmcnt(0)" ::: "memory");
    __builtin_amdgcn_sched_barrier(0);
    __builtin_amdgcn_s_barrier();
    __builtin_amdgcn_sched_barrier(0);
  };

  LOADAB(0, 0);
  LOADAB(1, 1);
  WRITE(0, 0);
  LOADAB(2, 0);
  BAR();

#pragma unroll
  for (int t = 0; t < 8; ++t) {
    if (t < 7) {
      if ((t + 1) & 1) {
        WRITE(1, 1);
        if (t + 3 < 8) LOADAB(t + 3, 1);
      } else {
        WRITE(0, 0);
        if (t + 3 < 8) LOADAB(t + 3, 0);
      }
    }
    COMP(t & 1);
    if (t < 7) BAR();
  }

#pragma unroll
  for (int m = 0; m < 2; ++m) {
#pragma unroll
    for (int r = 0; r < 4; ++r) {
      int grow = row0 + wm * 32 + m * 16 + l4 * 4 + r;
      if (grow < nrows) {
#pragma unroll
        for (int n = 0; n < 4; ++n) {
          int col = wn * 64 + n * 16 + l15;
          support[(size_t)grow * NHID + col] = (_Float16)acc[m][n][r];
        }
      }
    }
  }
}

__device__ __forceinline__ void bucketize_body(
    char* smem, const int* __restrict__ esrc, const int* __restrict__ edst,
    const float* __restrict__ ew, int* __restrict__ bcur, int* __restrict__ deg,
    int* __restrict__ bsrc, float* __restrict__ bw, int* __restrict__ bdst,
    int E, int nb, int bid) {
  int* lh = (int*)smem;
  int* lo = lh + 256;
  int* gbase = lo + 256;
  int* s_src = gbase + 256;
  float* s_w = (float*)(s_src + ACHUNK);
  int* s_dst = (int*)(s_w + ACHUNK);
  const int tid = threadIdx.x;
  const int base = bid * ACHUNK;
  const int cnt = min(ACHUNK, E - base);

  for (int t = tid; t < nb; t += 256) lh[t] = 0;
  __syncthreads();

  int my_s[8], my_d[8], my_t[8];
  float my_w[8];
#pragma unroll
  for (int i = 0; i < 8; ++i) {
    int idx = base + i * 256 + tid;
    if (idx < E) {
      my_s[i] = esrc[idx];
      my_d[i] = edst[idx];
      my_w[i] = ew[idx];
      my_t[i] = atomicAdd(&lh[my_d[i] >> BSH], 1);
      atomicAdd(&deg[my_d[i]], 1);            // fused histogram
    }
  }
  __syncthreads();
  if (tid == 0) {
    int run = 0;
    for (int b = 0; b < nb; ++b) { lo[b] = run; run += lh[b]; }
  }
  __syncthreads();
  if (tid < nb && lh[tid] > 0)
    gbase[tid] = tid * BSLOT + atomicAdd(&bcur[tid], lh[tid]);
  __syncthreads();
#pragma unroll
  for (int i = 0; i < 8; ++i) {
    int idx = base + i * 256 + tid;
    if (idx < E) {
      int p = lo[my_d[i] >> BSH] + my_t[i];
      s_src[p] = my_s[i];
      s_w[p] = my_w[i];
      s_dst[p] = my_d[i];
    }
  }
  __syncthreads();
  for (int j = tid; j < cnt; j += 256) {
    int d = s_dst[j];
    int b = d >> BSH;
    int g = gbase[b] + (j - lo[b]);
    bsrc[g] = s_src[j];
    bw[g] = s_w[j];
    bdst[g] = d;
  }
}

// ---- FAT, interleaved roles: bid%3==2 -> bucketize[bid/3], else gemm ----
__global__ __launch_bounds__(256, 3) void fat_kernel(
    const float* __restrict__ x, const __hip_bfloat16* __restrict__ W1t,
    _Float16* __restrict__ support, int nrows,
    const int* __restrict__ esrc, const int* __restrict__ edst,
    const float* __restrict__ ew, int* __restrict__ bcur, int* __restrict__ deg,
    int* __restrict__ bsrc, float* __restrict__ bw, int* __restrict__ bdst,
    int E, int nb) {
  __shared__ __align__(16) char smem[49152];   // union: gemm 48K | bucketize 27K
  const int bid = (int)blockIdx.x;
  if (bid % 3 == 2)
    bucketize_body(smem, esrc, edst, ew, bcur, deg, bsrc, bw, bdst, E, nb, bid / 3);
  else
    gemm1_body(smem, x, W1t, support, nrows, bid - bid / 3);
}

// ---- pass B: per-bucket scatter; stores (src, (w,w) packed f16x2) ----
__global__ __launch_bounds__(256) void bucket_scatter(
    const int* __restrict__ bcur, const int* __restrict__ bsrc,
    const float* __restrict__ bw, const int* __restrict__ bdst,
    int2* __restrict__ cwsrc, int n) {
  __shared__ int cur[1 << BSH];
  const int tid = threadIdx.x;
  const int d0 = blockIdx.x << BSH;
  for (int t = tid; t < (1 << BSH); t += 256) cur[t] = (d0 + t) << SLOTSH;
  __syncthreads();
  const int bstart = blockIdx.x * BSLOT;
  const int bend = bstart + bcur[blockIdx.x];
  for (int j = bstart + tid; j < bend; j += 256) {
    int d = bdst[j];
    int slot = atomicAdd(&cur[d - d0], 1);
    float w = bw[j];
    cwsrc[slot] = make_int2(bsrc[j], (int)pk2u(__builtin_amdgcn_cvt_pkrtz(w, w)));
  }
}

// ------- SpMM1, XCD-pinned feature slices, WAVE-UNIFORM edge loop -------
// slice = bid&3; wave = one node; 4 lane-groups of 16, group g covers edges
// j == g (mod 4). Trip count iters=ceil(dg/4) is wave-uniform; out-of-range
// j uses clamped source lane (valid data) with weight forced to 0, so every
// __shfl executes with ALL 64 lanes active (bpermute from inactive lanes is
// undefined -- round 22's bug).
__global__ __launch_bounds__(256) void spmm1_slice(
    const int* __restrict__ deg, const int2* __restrict__ cwsrc,
    const unsigned* __restrict__ supu, const float* __restrict__ b1,
    unsigned* __restrict__ hu, int n) {
  const int tid = threadIdx.x;
  const int wv = tid >> 6, lane = tid & 63;
  const int g = lane >> 4, fi = lane & 15;
  const int bid = (int)blockIdx.x;
  const int slice = bid & 3;
  const int node = (bid >> 2) * 4 + wv;
  if (node >= n) return;                        // wave-uniform exit
  const int dg = deg[node];
  int2 eself = (lane < dg) ? cwsrc[((size_t)node << SLOTSH) + lane] : make_int2(0, 0);
  const unsigned boff = (unsigned)(slice * 16 + fi);   // u32 index in 64-u32 row
  h16x2 accA = (h16x2){(_Float16)0, (_Float16)0};
  h16x2 accB = (h16x2){(_Float16)0, (_Float16)0};
  const int iters = (dg + 3) >> 2;              // wave-uniform trip count
  for (int kk = 0; kk < iters; kk += 2) {
    int j0 = g + kk * 4;
    int j1 = j0 + 4;
    int j0c = (j0 < dg) ? j0 : 0;
    int j1c = (j1 < dg) ? j1 : 0;
    int s0 = __shfl(eself.x, j0c, 64);
    unsigned w0 = (unsigned)__shfl(eself.y, j0c, 64);
    int s1 = __shfl(eself.x, j1c, 64);
    unsigned w1 = (unsigned)__shfl(eself.y, j1c, 64);
    if (j0 >= dg) w0 = 0u;
    if (j1 >= dg || kk + 1 >= iters) w1 = 0u;
    unsigned u0 = supu[((size_t)(unsigned)s0 << 6) | boff];
    unsigned u1 = supu[((size_t)(unsigned)s1 << 6) | boff];
    accA += u2a(u0) * u2a(w0);
    accB += u2a(u1) * u2a(w1);
  }
  h16x2 acc = accA + accB;
  acc += u2a((unsigned)__shfl_xor(*(int*)&acc, 16, 64));
  acc += u2a((unsigned)__shfl_xor(*(int*)&acc, 32, 64));
  if (lane < 16) {
    const float2 bb = *(const float2*)&b1[slice * 32 + fi * 2];
    float a0 = fmaxf((float)acc[0] + bb.x, 0.f);
    float a1 = fmaxf((float)acc[1] + bb.y, 0.f);
    unsigned pair = (unsigned)(unsigned short)f2bf(a0) |
                    ((unsigned)(unsigned short)f2bf(a1) << 16);
    hu[((size_t)node << 6) | boff] = pair;      // h: bf16 [N][128]
  }
}

// ------- GEMM2 (MFMA): s2[N,40] = h @ W2, 16 nodes/block, verified tail -------
__global__ __launch_bounds__(256) void gemm2_mfma(
    const unsigned* __restrict__ hu, const float* __restrict__ W2,
    _Float16* __restrict__ s2, int n) {
  __shared__ __align__(16) char sW[48 * 128 * 2];   // W2T[n][k] bf16 swizzled
  __shared__ __align__(16) char sH[16 * 128 * 2];   // h[row][k] bf16 swizzled
  const int tid = threadIdx.x;
  for (int i = tid; i < 48 * 128; i += 256) {
    int nn = i >> 7, k = i & 127;
    float v = (nn < NCLS) ? W2[k * NCLS + nn] : 0.f;
    int byte = (nn * 256 + k * 2) ^ ((nn & 7) << 4);
    *(short*)(sW + byte) = f2bf(v);
  }
  const int node0 = blockIdx.x * 16;
  for (int i = tid; i < 16 * 64; i += 256) {
    int r = i >> 6, k2 = i & 63;
    int nd = node0 + r;
    unsigned v = (nd < n) ? hu[((size_t)nd << 6) | (unsigned)k2] : 0u;
    int byte = (r * 256 + k2 * 4) ^ ((r & 7) << 4);
    *(unsigned*)(sH + byte) = v;
  }
  __syncthreads();
  const int wv = tid >> 6, f2 = tid & 63;
  if (wv < 3) {
    const int l15 = f2 & 15, l4 = f2 >> 4;
    f32x4 acc = (f32x4){0.f, 0.f, 0.f, 0.f};
#pragma unroll
    for (int kk = 0; kk < 4; ++kk) {
      int ka = (kk * 32 + l4 * 8) * 2;
      bf16x8 af = *(const bf16x8*)(sH + ((l15 * 256 + ka) ^ ((l15 & 7) << 4)));
      int nrow = wv * 16 + l15;
      bf16x8 bf = *(const bf16x8*)(sW + ((nrow * 256 + ka) ^ ((nrow & 7) << 4)));
      acc = __builtin_amdgcn_mfma_f32_16x16x32_bf16(af, bf, acc, 0, 0, 0);
    }
    int col = wv * 16 + l15;
    if (col < NCLS) {
#pragma unroll
      for (int r = 0; r < 4; ++r) {
        int onode = node0 + l4 * 4 + r;
        if (onode < n) s2[(size_t)onode * NCLS + col] = (_Float16)acc[r];
      }
    }
  }
}

// ------- SpMM2 gather: 1 wave/node, all lanes live, packed f16 FMA -------
__global__ __launch_bounds__(256) void spmm2_gather(
    const int* __restrict__ deg, const int2* __restrict__ cwsrc,
    const _Float16* __restrict__ s2,
    const float* __restrict__ b2, float* __restrict__ out, int n) {
  const int w = threadIdx.x >> 6;
  const int f2 = threadIdx.x & 63;
  const int node = blockIdx.x * 4 + w;
  if (node >= n) return;                             // wave-uniform exit
  const int dg = deg[node];
  int2 eself = (f2 < dg) ? cwsrc[((size_t)node << SLOTSH) + f2] : make_int2(0, 0);
  const unsigned f2c = (f2 < 20) ? (unsigned)f2 : 0u;
  h16x2 accA = (h16x2){(_Float16)0, (_Float16)0};
  h16x2 accB = (h16x2){(_Float16)0, (_Float16)0};
  const unsigned* sp = (const unsigned*)s2;
  int j = 0;
  for (; j + 7 < dg; j += 8) {
#pragma unroll
    for (int q = 0; q < 8; ++q) {
      int s = __builtin_amdgcn_readlane(eself.x, j + q);
      unsigned w2u = (unsigned)__builtin_amdgcn_readlane(eself.y, j + q);
      unsigned u = sp[(size_t)(unsigned)s * 20u + f2c];
      if (q & 1) accB += u2a(u) * u2a(w2u);
      else       accA += u2a(u) * u2a(w2u);
    }
  }
  for (; j < dg; ++j) {
    int s = __builtin_amdgcn_readlane(eself.x, j);
    unsigned w2u = (unsigned)__builtin_amdgcn_readlane(eself.y, j);
    unsigned u = sp[(size_t)(unsigned)s * 20u + f2c];
    if (j & 1) accB += u2a(u) * u2a(w2u);
    else       accA += u2a(u) * u2a(w2u);
  }
  if (f2 < 20) {
    h16x2 acc2 = accA + accB;
    float2 o;
    o.x = (float)acc2[0] + b2[f2 * 2];
    o.y = (float)acc2[1] + b2[f2 * 2 + 1];
    *(float2*)&out[(size_t)node * NCLS + f2 * 2] = o;
  }
}

extern "C" void kernel_launch(void* const* d_in, const int* in_sizes, int n_in,
                              void* d_out, int out_size, void* d_ws, size_t ws_size,
                              hipStream_t stream) {
  const float* x   = (const float*)d_in[0];
  const float* W1  = (const float*)d_in[1];
  const float* b1  = (const float*)d_in[2];
  const float* W2  = (const float*)d_in[3];
  const float* b2  = (const float*)d_in[4];
  const int* esrc  = (const int*)d_in[5];
  const int* edst  = (const int*)d_in[6];
  const float* ew  = (const float*)d_in[7];
  float* out = (float*)d_out;

  const int N = in_sizes[0] / NFEAT;           // 50000
  const int E = in_sizes[5];                   // 800000
  const int NB = (N + (1 << BSH) - 1) >> BSH;  // 196 buckets

  char* ws = (char*)d_ws;
  size_t off = 0;
  auto alloc = [&](size_t bytes) {
    void* p = ws + off;
    off += (bytes + 255) & ~(size_t)255;
    return p;
  };
  int2*  cwsrc = (int2*)alloc((size_t)N * (1 << SLOTSH) * 8);   // 25.6 MB
  int*   degb  = (int*)alloc((size_t)((N + NB + 3) & ~3) * 4);  // deg | bcur
  int*   deg   = degb;
  int*   bcur  = degb + N;
  int*   bsrc  = (int*)alloc((size_t)NB * BSLOT * 4);
  float* bw    = (float*)alloc((size_t)NB * BSLOT * 4);
  int*   bdst  = (int*)alloc((size_t)NB * BSLOT * 4);
  __hip_bfloat16* W1t = (__hip_bfloat16*)alloc((size_t)NHID * NFEAT * 2);
  _Float16* support   = (_Float16*)alloc((size_t)N * NHID * 2);
  _Float16* s2        = (_Float16*)alloc((size_t)N * NCLS * 2);
  // h (bf16 [N][128] = 12.8MB) aliases bsrc/bw/bdst (14.4MB contiguous, dead
  // after bucket_scatter which completes before spmm1_slice writes h)
  unsigned* hu = (unsigned*)bsrc;

  // ---- w1t + zero (independent preludes, one launch) ----
  const int nz4 = (N + NB + 3) / 4;
  w1t_zero<<<8 + (nz4 + 255) / 256, 256, 0, stream>>>(W1, W1t, (int4*)degb, nz4);

  // ---- FAT: gemm1 (782) and bucketize (391) interleaved 2:1 ----
  const int GEMMB = (N + 63) / 64;                  // 782
  const int BUCKB = (E + ACHUNK - 1) / ACHUNK;      // 391
  fat_kernel<<<GEMMB + BUCKB, 256, 0, stream>>>(
      x, W1t, support, N,
      esrc, edst, ew, bcur, deg, bsrc, bw, bdst, E, NB);

  bucket_scatter<<<NB, 256, 0, stream>>>(bcur, bsrc, bw, bdst, cwsrc, N);

  // ---- layer 1 aggregation: 4 XCD-pinned feature slices ----
  const int NGRP = (N + 3) / 4;                     // 4 nodes per block
  spmm1_slice<<<NGRP * 4, 256, 0, stream>>>(
      deg, cwsrc, (const unsigned*)support, b1, hu, N);

  // ---- layer 2 dense (MFMA) ----
  gemm2_mfma<<<(N + 15) / 16, 256, 0, stream>>>(hu, W2, s2, N);

  // ---- layer 2 aggregation ----
  spmm2_gather<<<(N + 3) / 4, 256, 0, stream>>>(deg, cwsrc, s2, b2, out, N);
}

// Round 24
// 157.497 us; speedup vs baseline: 1.2557x; 1.2557x over previous
//
#include <hip/hip_runtime.h>
#include <hip/hip_bf16.h>

// GCN forward: out = spmm(A, relu(spmm(A, x@W1)+b1) @ W2) + b2
// N=50000, F=512, H=128, C=40, E=800000
// Round 24: REVERT to round-21 structure (157.5us; round 22/23's XCD-slice
// regressed to 197.8 -- FETCH went UP from slot-row replication). One change:
// gemm1 prefetch deepened (A depth-3, B depth-2) to raise in-flight bytes --
// the x-stream runs at 1.7TB/s vs 6.3 floor-implied, under-pipelined.

#define NFEAT 512
#define NHID  128
#define NCLS  40
#define BSH   8            // 256 dsts per bucket
#define SLOTSH 6           // 64 edge slots per node (max deg ~40)
#define BSLOT 6144         // bucket scratch slots (mean 4082, +32 sigma)
#define ACHUNK 2048        // edges per bucketize block

typedef __attribute__((ext_vector_type(8))) short bf16x8;
typedef __attribute__((ext_vector_type(4))) float f32x4;
typedef __fp16 cvt16x2 __attribute__((ext_vector_type(2)));    // builtin boundary
typedef _Float16 h16x2 __attribute__((ext_vector_type(2)));    // packed arithmetic

__device__ inline short f2bf(float f) {
  __hip_bfloat16 b = __float2bfloat16(f);
  return *reinterpret_cast<short*>(&b);
}

__device__ inline bf16x8 cvt8(float4 a, float4 b) {
  bf16x8 r;
  r[0] = f2bf(a.x); r[1] = f2bf(a.y); r[2] = f2bf(a.z); r[3] = f2bf(a.w);
  r[4] = f2bf(b.x); r[5] = f2bf(b.y); r[6] = f2bf(b.z); r[7] = f2bf(b.w);
  return r;
}

__device__ inline unsigned pk2u(cvt16x2 v) { union { cvt16x2 h; unsigned u; } x; x.h = v; return x.u; }
__device__ inline h16x2   u2a(unsigned u)  { union { h16x2 h; unsigned u; } x; x.u = u; return x.h; }

// ---------------- w1t + zero (fused) ----------------
__global__ __launch_bounds__(256) void w1t_zero(
    const float* __restrict__ W1, __hip_bfloat16* __restrict__ W1t,
    int4* __restrict__ zp, int n4) {
  __shared__ float t[64][129];
  const int tid = threadIdx.x;
  if (blockIdx.x < 8) {
    const int k0 = blockIdx.x * 64;
#pragma unroll
    for (int i = 0; i < 8; ++i) {
      int f = i * 256 + tid;
      int r = f >> 5, c = (f & 31) << 2;
      float4 v = *(const float4*)&W1[(size_t)(k0 + r) * NHID + c];
      t[r][c] = v.x; t[r][c + 1] = v.y; t[r][c + 2] = v.z; t[r][c + 3] = v.w;
    }
    __syncthreads();
#pragma unroll
    for (int i = 0; i < 32; ++i) {
      int o = i * 256 + tid;
      int k = o & 63, n = o >> 6;
      W1t[(size_t)n * NFEAT + k0 + k] = __float2bfloat16(t[k][n]);
    }
  } else {
    int i = (blockIdx.x - 8) * 256 + tid;
    if (i < n4) zp[i] = make_int4(0, 0, 0, 0);
  }
}

// ---------------- FAT kernel bodies ----------------
// A prefetch depth-3 (ra0..ra2, set = tile%3), B depth-2 (rb0..rb1, set = tile&1),
// LDS double buffer (buf = tile&1). Raw s_barrier, no vmcnt drain.
__device__ __forceinline__ void gemm1_body(
    char* smem, const float* __restrict__ x, const __hip_bfloat16* __restrict__ W1t,
    _Float16* __restrict__ support, int nrows, int bid) {
  char* sA0 = smem;                 // 2 x 8KB  = [0, 16K)
  char* sB0 = smem + 16384;         // 2 x 16KB = [16K, 48K)
  const int tid = threadIdx.x;
  const int lane = tid & 63;
  const int wid = tid >> 6;
  const int wm = wid >> 1, wn = wid & 1;
  const int row0 = bid * 64;
  const int l15 = lane & 15, l4 = lane >> 4;

  const int s_ar = tid >> 2;
  const int s_ac = (tid & 3) * 16;
  const int s_br = tid >> 1;
  const int s_bc = (tid & 1) * 32;
  const bool a_ok = (row0 + s_ar) < nrows;
  const float* aptr = &x[(size_t)(row0 + s_ar) * NFEAT + s_ac];
  const uint4* bptr = (const uint4*)&W1t[(size_t)s_br * NFEAT + s_bc];

  f32x4 acc[2][4];
#pragma unroll
  for (int m = 0; m < 2; ++m)
#pragma unroll
    for (int n = 0; n < 4; ++n) acc[m][n] = (f32x4){0.f, 0.f, 0.f, 0.f};

  float4 ra0[4], ra1[4], ra2[4];
  uint4 rb0[4], rb1[4];

  auto LOADA = [&](int kt, int sel) {
    if (sel == 0) {
      if (a_ok) {
        const float4* p = (const float4*)(aptr + (size_t)kt * 64);
#pragma unroll
        for (int i = 0; i < 4; ++i) ra0[i] = p[i];
      } else {
        float4 z = make_float4(0.f, 0.f, 0.f, 0.f);
#pragma unroll
        for (int i = 0; i < 4; ++i) ra0[i] = z;
      }
    } else if (sel == 1) {
      if (a_ok) {
        const float4* p = (const float4*)(aptr + (size_t)kt * 64);
#pragma unroll
        for (int i = 0; i < 4; ++i) ra1[i] = p[i];
      } else {
        float4 z = make_float4(0.f, 0.f, 0.f, 0.f);
#pragma unroll
        for (int i = 0; i < 4; ++i) ra1[i] = z;
      }
    } else {
      if (a_ok) {
        const float4* p = (const float4*)(aptr + (size_t)kt * 64);
#pragma unroll
        for (int i = 0; i < 4; ++i) ra2[i] = p[i];
      } else {
        float4 z = make_float4(0.f, 0.f, 0.f, 0.f);
#pragma unroll
        for (int i = 0; i < 4; ++i) ra2[i] = z;
      }
    }
  };
  auto LOADB = [&](int kt, int sel) {
    const uint4* q = bptr + (size_t)kt * 8;
    if (sel == 0) {
#pragma unroll
      for (int i = 0; i < 4; ++i) rb0[i] = q[i];
    } else {
#pragma unroll
      for (int i = 0; i < 4; ++i) rb1[i] = q[i];
    }
  };
  auto WRITE = [&](int buf, int sa, int sb) {
    bf16x8 c0, c1;
    if (sa == 0)      { c0 = cvt8(ra0[0], ra0[1]); c1 = cvt8(ra0[2], ra0[3]); }
    else if (sa == 1) { c0 = cvt8(ra1[0], ra1[1]); c1 = cvt8(ra1[2], ra1[3]); }
    else              { c0 = cvt8(ra2[0], ra2[1]); c1 = cvt8(ra2[2], ra2[3]); }
    int swa = (s_ar & 7) << 4;
    char* sA = sA0 + buf * 8192;
    *(bf16x8*)(sA + ((s_ar * 128 + s_ac * 2) ^ swa)) = c0;
    *(bf16x8*)(sA + ((s_ar * 128 + s_ac * 2 + 16) ^ swa)) = c1;
    int swb = (s_br & 7) << 4;
    char* sB = sB0 + buf * 16384;
#pragma unroll
    for (int i = 0; i < 4; ++i) {
      uint4 v = (sb == 0) ? rb0[i] : rb1[i];
      *(uint4*)(sB + ((s_br * 128 + s_bc * 2 + i * 16) ^ swb)) = v;
    }
  };
  auto COMP = [&](int buf) {
    char* sA = sA0 + buf * 8192;
    char* sB = sB0 + buf * 16384;
#pragma unroll
    for (int kk = 0; kk < 64; kk += 32) {
      bf16x8 a[2], b[4];
      int cb = (kk + l4 * 8) * 2;
#pragma unroll
      for (int m = 0; m < 2; ++m) {
        int r = wm * 32 + m * 16 + l15;
        a[m] = *(const bf16x8*)(sA + ((r * 128 + cb) ^ ((r & 7) << 4)));
      }
#pragma unroll
      for (int n = 0; n < 4; ++n) {
        int r = wn * 64 + n * 16 + l15;
        b[n] = *(const bf16x8*)(sB + ((r * 128 + cb) ^ ((r & 7) << 4)));
      }
#pragma unroll
      for (int m = 0; m < 2; ++m)
#pragma unroll
        for (int n = 0; n < 4; ++n)
          acc[m][n] = __builtin_amdgcn_mfma_f32_16x16x32_bf16(a[m], b[n], acc[m][n], 0, 0, 0);
    }
  };
  auto BAR = [&]() {
    asm volatile("s_waitcnt lgkmcnt(0)" ::: "memory");
    __builtin_amdgcn_sched_barrier(0);
    __builtin_amdgcn_s_barrier();
    __builtin_amdgcn_sched_barrier(0);
  };

  // prologue: A tiles 0,1,2 -> sets 0,1,2; B tiles 0,1 -> sets 0,1.
  // After WRITE(0): A tile3 -> set0, B tile2 -> set0 (both just consumed).
  LOADA(0, 0); LOADB(0, 0);
  LOADA(1, 1); LOADB(1, 1);
  LOADA(2, 2);
  WRITE(0, 0, 0);
  LOADB(2, 0);
  LOADA(3, 0);
  BAR();

#pragma unroll
  for (int t = 0; t < 8; ++t) {
    if (t < 7) {
      const int tile = t + 1;               // compile-time (loop unrolled)
      WRITE(tile & 1, tile % 3, tile & 1);
      if (tile + 3 <= 7) LOADA(tile + 3, (tile + 3) % 3);
      if (tile + 2 <= 7) LOADB(tile + 2, (tile + 2) & 1);
    }
    COMP(t & 1);
    if (t < 7) BAR();
  }

#pragma unroll
  for (int m = 0; m < 2; ++m) {
#pragma unroll
    for (int r = 0; r < 4; ++r) {
      int grow = row0 + wm * 32 + m * 16 + l4 * 4 + r;
      if (grow < nrows) {
#pragma unroll
        for (int n = 0; n < 4; ++n) {
          int col = wn * 64 + n * 16 + l15;
          support[(size_t)grow * NHID + col] = (_Float16)acc[m][n][r];
        }
      }
    }
  }
}

__device__ __forceinline__ void bucketize_body(
    char* smem, const int* __restrict__ esrc, const int* __restrict__ edst,
    const float* __restrict__ ew, int* __restrict__ bcur, int* __restrict__ deg,
    int* __restrict__ bsrc, float* __restrict__ bw, int* __restrict__ bdst,
    int E, int nb, int bid) {
  int* lh = (int*)smem;
  int* lo = lh + 256;
  int* gbase = lo + 256;
  int* s_src = gbase + 256;
  float* s_w = (float*)(s_src + ACHUNK);
  int* s_dst = (int*)(s_w + ACHUNK);
  const int tid = threadIdx.x;
  const int base = bid * ACHUNK;
  const int cnt = min(ACHUNK, E - base);

  for (int t = tid; t < nb; t += 256) lh[t] = 0;
  __syncthreads();

  int my_s[8], my_d[8], my_t[8];
  float my_w[8];
#pragma unroll
  for (int i = 0; i < 8; ++i) {
    int idx = base + i * 256 + tid;
    if (idx < E) {
      my_s[i] = esrc[idx];
      my_d[i] = edst[idx];
      my_w[i] = ew[idx];
      my_t[i] = atomicAdd(&lh[my_d[i] >> BSH], 1);
      atomicAdd(&deg[my_d[i]], 1);            // fused histogram
    }
  }
  __syncthreads();
  if (tid == 0) {
    int run = 0;
    for (int b = 0; b < nb; ++b) { lo[b] = run; run += lh[b]; }
  }
  __syncthreads();
  if (tid < nb && lh[tid] > 0)
    gbase[tid] = tid * BSLOT + atomicAdd(&bcur[tid], lh[tid]);
  __syncthreads();
#pragma unroll
  for (int i = 0; i < 8; ++i) {
    int idx = base + i * 256 + tid;
    if (idx < E) {
      int p = lo[my_d[i] >> BSH] + my_t[i];
      s_src[p] = my_s[i];
      s_w[p] = my_w[i];
      s_dst[p] = my_d[i];
    }
  }
  __syncthreads();
  for (int j = tid; j < cnt; j += 256) {
    int d = s_dst[j];
    int b = d >> BSH;
    int g = gbase[b] + (j - lo[b]);
    bsrc[g] = s_src[j];
    bw[g] = s_w[j];
    bdst[g] = d;
  }
}

// ---- FAT, interleaved roles: bid%3==2 -> bucketize[bid/3], else gemm ----
__global__ __launch_bounds__(256, 3) void fat_kernel(
    const float* __restrict__ x, const __hip_bfloat16* __restrict__ W1t,
    _Float16* __restrict__ support, int nrows,
    const int* __restrict__ esrc, const int* __restrict__ edst,
    const float* __restrict__ ew, int* __restrict__ bcur, int* __restrict__ deg,
    int* __restrict__ bsrc, float* __restrict__ bw, int* __restrict__ bdst,
    int E, int nb) {
  __shared__ __align__(16) char smem[49152];   // union: gemm 48K | bucketize 27K
  const int bid = (int)blockIdx.x;
  if (bid % 3 == 2)
    bucketize_body(smem, esrc, edst, ew, bcur, deg, bsrc, bw, bdst, E, nb, bid / 3);
  else
    gemm1_body(smem, x, W1t, support, nrows, bid - bid / 3);
}

// ---- pass B: per-bucket scatter; stores (src, (w,w) packed f16x2) ----
__global__ __launch_bounds__(256) void bucket_scatter(
    const int* __restrict__ bcur, const int* __restrict__ bsrc,
    const float* __restrict__ bw, const int* __restrict__ bdst,
    int2* __restrict__ cwsrc, int n) {
  __shared__ int cur[1 << BSH];
  const int tid = threadIdx.x;
  const int d0 = blockIdx.x << BSH;
  for (int t = tid; t < (1 << BSH); t += 256) cur[t] = (d0 + t) << SLOTSH;
  __syncthreads();
  const int bstart = blockIdx.x * BSLOT;
  const int bend = bstart + bcur[blockIdx.x];
  for (int j = bstart + tid; j < bend; j += 256) {
    int d = bdst[j];
    int slot = atomicAdd(&cur[d - d0], 1);
    float w = bw[j];
    cwsrc[slot] = make_int2(bsrc[j], (int)pk2u(__builtin_amdgcn_cvt_pkrtz(w, w)));
  }
}

// ------- SpMM1+GEMM2 fused: 1024 threads = 16 waves, ONE node per wave
//         (full TLP), gemv tail via mfma_f32_16x16x32_bf16 (waves 0..2) -------
__global__ __launch_bounds__(1024) void spmm1_fused(
    const int* __restrict__ deg, const int2* __restrict__ cwsrc,
    const _Float16* __restrict__ support, const float* __restrict__ b1,
    const float* __restrict__ W2, _Float16* __restrict__ s2, int n) {
  __shared__ __align__(16) char sW[48 * 128 * 2];   // W2T[n][k] bf16 swizzled, 12KB
  __shared__ __align__(16) char sH[16 * 128 * 2];   // h[row][k] bf16 swizzled, 4KB
  const int tid = threadIdx.x;
  for (int i = tid; i < 48 * 128; i += 1024) {
    int nn = i >> 7, k = i & 127;
    float v = (nn < NCLS) ? W2[k * NCLS + nn] : 0.f;
    int byte = (nn * 256 + k * 2) ^ ((nn & 7) << 4);
    *(short*)(sW + byte) = f2bf(v);
  }

  const int wv = tid >> 6, f2 = tid & 63;       // wv = 0..15, one node per wave
  const int node0 = blockIdx.x * 16;
  const int node = node0 + wv;
  const float2 bb = *(const float2*)&b1[f2 * 2];
  const unsigned* sp = (const unsigned*)support;

  const int dg = (node < n) ? deg[node] : 0;
  int2 eself = (f2 < dg) ? cwsrc[((size_t)node << SLOTSH) + f2] : make_int2(0, 0);
  h16x2 accA = (h16x2){(_Float16)0, (_Float16)0};
  h16x2 accB = (h16x2){(_Float16)0, (_Float16)0};
  int j = 0;
  for (; j + 7 < dg; j += 8) {
#pragma unroll
    for (int q = 0; q < 8; ++q) {
      int s = __builtin_amdgcn_readlane(eself.x, j + q);
      unsigned w2u = (unsigned)__builtin_amdgcn_readlane(eself.y, j + q);
      unsigned u = sp[((size_t)(unsigned)s << 6) | (unsigned)f2];
      if (q & 1) accB += u2a(u) * u2a(w2u);
      else       accA += u2a(u) * u2a(w2u);
    }
  }
  for (; j < dg; ++j) {
    int s = __builtin_amdgcn_readlane(eself.x, j);
    unsigned w2u = (unsigned)__builtin_amdgcn_readlane(eself.y, j);
    unsigned u = sp[((size_t)(unsigned)s << 6) | (unsigned)f2];
    if (j & 1) accB += u2a(u) * u2a(w2u);
    else       accA += u2a(u) * u2a(w2u);
  }
  h16x2 acc2 = accA + accB;
  float a0 = fmaxf((float)acc2[0] + bb.x, 0.f);
  float a1 = fmaxf((float)acc2[1] + bb.y, 0.f);
  {
    int byte = (wv * 256 + f2 * 4) ^ ((wv & 7) << 4);
    unsigned pair = (unsigned)(unsigned short)f2bf(a0) |
                    ((unsigned)(unsigned short)f2bf(a1) << 16);
    *(unsigned*)(sH + byte) = pair;
  }
  __syncthreads();
  // MFMA tail: waves 0..2 each compute 16 nodes x 16 classes (K=128 in 4 steps)
  if (wv < 3) {
    const int l15 = f2 & 15, l4 = f2 >> 4;
    f32x4 acc = (f32x4){0.f, 0.f, 0.f, 0.f};
#pragma unroll
    for (int kk = 0; kk < 4; ++kk) {
      int ka = (kk * 32 + l4 * 8) * 2;
      bf16x8 af = *(const bf16x8*)(sH + ((l15 * 256 + ka) ^ ((l15 & 7) << 4)));
      int nrow = wv * 16 + l15;
      bf16x8 bf = *(const bf16x8*)(sW + ((nrow * 256 + ka) ^ ((nrow & 7) << 4)));
      acc = __builtin_amdgcn_mfma_f32_16x16x32_bf16(af, bf, acc, 0, 0, 0);
    }
    int col = wv * 16 + l15;
    if (col < NCLS) {
#pragma unroll
      for (int r = 0; r < 4; ++r) {
        int onode = node0 + l4 * 4 + r;
        if (onode < n) s2[(size_t)onode * NCLS + col] = (_Float16)acc[r];
      }
    }
  }
}

// ------- SpMM2 gather: 1 wave/node, all lanes live, packed f16 FMA -------
__global__ __launch_bounds__(256) void spmm2_gather(
    const int* __restrict__ deg, const int2* __restrict__ cwsrc,
    const _Float16* __restrict__ s2,
    const float* __restrict__ b2, float* __restrict__ out, int n) {
  const int w = threadIdx.x >> 6;
  const int f2 = threadIdx.x & 63;
  const int node = blockIdx.x * 4 + w;
  if (node >= n) return;                             // wave-uniform exit
  const int dg = deg[node];
  int2 eself = (f2 < dg) ? cwsrc[((size_t)node << SLOTSH) + f2] : make_int2(0, 0);
  const unsigned f2c = (f2 < 20) ? (unsigned)f2 : 0u;
  h16x2 accA = (h16x2){(_Float16)0, (_Float16)0};
  h16x2 accB = (h16x2){(_Float16)0, (_Float16)0};
  const unsigned* sp = (const unsigned*)s2;
  int j = 0;
  for (; j + 7 < dg; j += 8) {
#pragma unroll
    for (int q = 0; q < 8; ++q) {
      int s = __builtin_amdgcn_readlane(eself.x, j + q);
      unsigned w2u = (unsigned)__builtin_amdgcn_readlane(eself.y, j + q);
      unsigned u = sp[(size_t)(unsigned)s * 20u + f2c];
      if (q & 1) accB += u2a(u) * u2a(w2u);
      else       accA += u2a(u) * u2a(w2u);
    }
  }
  for (; j < dg; ++j) {
    int s = __builtin_amdgcn_readlane(eself.x, j);
    unsigned w2u = (unsigned)__builtin_amdgcn_readlane(eself.y, j);
    unsigned u = sp[(size_t)(unsigned)s * 20u + f2c];
    if (j & 1) accB += u2a(u) * u2a(w2u);
    else       accA += u2a(u) * u2a(w2u);
  }
  if (f2 < 20) {
    h16x2 acc2 = accA + accB;
    float2 o;
    o.x = (float)acc2[0] + b2[f2 * 2];
    o.y = (float)acc2[1] + b2[f2 * 2 + 1];
    *(float2*)&out[(size_t)node * NCLS + f2 * 2] = o;
  }
}

extern "C" void kernel_launch(void* const* d_in, const int* in_sizes, int n_in,
                              void* d_out, int out_size, void* d_ws, size_t ws_size,
                              hipStream_t stream) {
  const float* x   = (const float*)d_in[0];
  const float* W1  = (const float*)d_in[1];
  const float* b1  = (const float*)d_in[2];
  const float* W2  = (const float*)d_in[3];
  const float* b2  = (const float*)d_in[4];
  const int* esrc  = (const int*)d_in[5];
  const int* edst  = (const int*)d_in[6];
  const float* ew  = (const float*)d_in[7];
  float* out = (float*)d_out;

  const int N = in_sizes[0] / NFEAT;           // 50000
  const int E = in_sizes[5];                   // 800000
  const int NB = (N + (1 << BSH) - 1) >> BSH;  // 196 buckets

  char* ws = (char*)d_ws;
  size_t off = 0;
  auto alloc = [&](size_t bytes) {
    void* p = ws + off;
    off += (bytes + 255) & ~(size_t)255;
    return p;
  };
  int2*  cwsrc = (int2*)alloc((size_t)N * (1 << SLOTSH) * 8);   // 25.6 MB
  int*   degb  = (int*)alloc((size_t)((N + NB + 3) & ~3) * 4);  // deg | bcur
  int*   deg   = degb;
  int*   bcur  = degb + N;
  int*   bsrc  = (int*)alloc((size_t)NB * BSLOT * 4);
  float* bw    = (float*)alloc((size_t)NB * BSLOT * 4);
  int*   bdst  = (int*)alloc((size_t)NB * BSLOT * 4);
  __hip_bfloat16* W1t = (__hip_bfloat16*)alloc((size_t)NHID * NFEAT * 2);
  _Float16* support   = (_Float16*)alloc((size_t)N * NHID * 2);
  _Float16* s2        = (_Float16*)alloc((size_t)N * NCLS * 2);

  // ---- w1t + zero (independent preludes, one launch) ----
  const int nz4 = (N + NB + 3) / 4;
  w1t_zero<<<8 + (nz4 + 255) / 256, 256, 0, stream>>>(W1, W1t, (int4*)degb, nz4);

  // ---- FAT: gemm1 (782) and bucketize (391) interleaved 2:1 ----
  const int GEMMB = (N + 63) / 64;                  // 782
  const int BUCKB = (E + ACHUNK - 1) / ACHUNK;      // 391
  fat_kernel<<<GEMMB + BUCKB, 256, 0, stream>>>(
      x, W1t, support, N,
      esrc, edst, ew, bcur, deg, bsrc, bw, bdst, E, NB);

  bucket_scatter<<<NB, 256, 0, stream>>>(bcur, bsrc, bw, bdst, cwsrc, N);

  // ---- layer 1 aggregation + fused layer-2 dense (MFMA tail) ----
  spmm1_fused<<<(N + 15) / 16, 1024, 0, stream>>>(deg, cwsrc, support, b1, W2, s2, N);

  // ---- layer 2 aggregation ----
  spmm2_gather<<<(N + 3) / 4, 256, 0, stream>>>(deg, cwsrc, s2, b2, out, N);
}